// Round 1
// baseline (1092.924 us; speedup 1.0000x reference)
//
#include <hip/hip_runtime.h>
#include <hip/hip_bf16.h>

typedef __bf16 bf16_t;
typedef __bf16 bf16x8 __attribute__((ext_vector_type(8)));
typedef float  f32x4  __attribute__((ext_vector_type(4)));

static __device__ __forceinline__ f32x4 mfma16(bf16x8 a, bf16x8 b, f32x4 c) {
    return __builtin_amdgcn_mfma_f32_16x16x32_bf16(a, b, c, 0, 0, 0);
}

// ws fragment-layout weight offsets (bf16 elements). Fragment block = 512
// elems = (64 lanes x 8 elems); block index = tile*frags + f.
#define OFF_W10 0
#define OFF_W11 86016
#define OFF_W12 98304
#define OFF_W20 101376
#define OFF_W21 150528
#define OFF_W22 162816
#define W_TOTAL 165888

// Convert fp32 weights (K,N) row-major into bf16 MFMA B-fragment order:
// elem ((tile*frags+f)*64 + lane)*8 + j  <-  W[k = f*32 + (lane>>4)*8 + j][n = tile*16 + (lane&15)]
__global__ void prep_weights(const float* __restrict__ W10, const float* __restrict__ W11,
                             const float* __restrict__ W12, const float* __restrict__ W20,
                             const float* __restrict__ W21, const float* __restrict__ W22,
                             bf16_t* __restrict__ ws) {
    int idx = blockIdx.x * 256 + threadIdx.x;
    if (idx >= W_TOTAL) return;
    const float* src; int K, N, off;
    if      (idx < OFF_W11) { src = W10; K = 128; N = 672; off = OFF_W10; }
    else if (idx < OFF_W12) { src = W11; K = 64;  N = 192; off = OFF_W11; }
    else if (idx < OFF_W20) { src = W12; K = 32;  N = 96;  off = OFF_W12; }
    else if (idx < OFF_W21) { src = W20; K = 384; N = 128; off = OFF_W20; }
    else if (idx < OFF_W22) { src = W21; K = 192; N = 64;  off = OFF_W21; }
    else                    { src = W22; K = 96;  N = 32;  off = OFF_W22; }
    int local = idx - off;
    int j    = local & 7;
    int lane = (local >> 3) & 63;
    int tf   = local >> 9;           // tile*frags + f
    int frags = K >> 5;
    int f    = tf % frags;
    int tile = tf / frags;
    int k = f * 32 + ((lane >> 4) << 3) + j;
    int n = tile * 16 + (lane & 15);
    ws[idx] = (bf16_t)src[k * N + n];
}

// LDS strides (bf16 elems), padded for bank rotation, 16B-aligned rows.
#define XDE_S   488   // staged x, de-interleaved:  [16][488]
#define MID0_S  392   // mid0 (scalars, 384):       [16][392]
#define MID1_S  200   // mid1 per i (192):          [16][200], base i*3200
#define MID2_S  104   // mid2 per i (96):           [16][104], base i*1664
#define GATE_S  296   // gates (288):               [16][296]

__global__ __launch_bounds__(256)
void ffn_kernel(const float* __restrict__ x, const float* __restrict__ attr,
                const float* __restrict__ b1, const float* __restrict__ b2,
                const bf16_t* __restrict__ wf, float* __restrict__ out) {
    __shared__ bf16_t smid[9600];           // 19200 B: xde / mid0 / mid1 x3 / mid2 x5 (reused)
    __shared__ bf16_t sgate[16 * GATE_S];   // 9472 B
    __shared__ float  sattr[16];

    const int tid   = threadIdx.x;
    const int lane  = tid & 63;
    const int w     = tid >> 6;       // wave id 0..3
    const int rlane = lane & 15;      // A row / B col / C col
    const int q     = lane >> 4;      // k-subgroup / C row-group
    const int rowbase = blockIdx.x * 16;

    // ---- stage x -> smid as de-interleaved bf16 ----
    // col<128 -> col; col in [128,320): m=(c-128)/3,i=%3 -> 128+i*64+m;
    // col>=320: m=(c-320)/5,i=%5 -> 320+i*32+m
    for (int it = 0; it < 8; ++it) {
        int idx = tid + it * 256;
        if (idx < 1920) {
            int row = idx / 120;
            int c4  = idx - row * 120;
            const float4 v = ((const float4*)(x + (size_t)(rowbase + row) * 480))[c4];
            float vals[4] = {v.x, v.y, v.z, v.w};
            int base = c4 * 4;
#pragma unroll
            for (int e = 0; e < 4; ++e) {
                int col = base + e;
                int dc;
                if (col < 128) dc = col;
                else if (col < 320) { int r = col - 128; int m = r / 3; int i = r - m * 3; dc = 128 + i * 64 + m; }
                else                { int r = col - 320; int m = r / 5; int i = r - m * 5; dc = 320 + i * 32 + m; }
                smid[row * XDE_S + dc] = (bf16_t)vals[e];
            }
        }
    }
    if (tid < 16) sattr[tid] = attr[rowbase + tid];
    __syncthreads();

    // ---- extract all A fragments into registers (each wave its own copy) ----
    bf16x8 a0[4], a1[3][2], a2[5];
    {
        int rb = rlane * XDE_S + q * 8;
#pragma unroll
        for (int f = 0; f < 4; ++f) a0[f] = *(const bf16x8*)&smid[rb + f * 32];
#pragma unroll
        for (int i = 0; i < 3; ++i)
#pragma unroll
            for (int f = 0; f < 2; ++f) a1[i][f] = *(const bf16x8*)&smid[rb + 128 + i * 64 + f * 32];
#pragma unroll
        for (int i = 0; i < 5; ++i) a2[i] = *(const bf16x8*)&smid[rb + 320 + i * 32];
    }
    __syncthreads();   // xde dead; smid reused as mid buffers below

    // ---- Phase 1, l=0: 42 col-tiles; scalars->mid0, gates->sgate ----
    {
        const float inv = 0.088388347648318447f;  // 1/sqrt(128)
        for (int t = w; t < 42; t += 4) {
            f32x4 acc = {0.f, 0.f, 0.f, 0.f};
            const bf16_t* wb = wf + OFF_W10 + ((t * 4) << 9) + (lane << 3);
#pragma unroll
            for (int f = 0; f < 4; ++f) {
                bf16x8 b = *(const bf16x8*)(wb + (f << 9));
                acc = mfma16(a0[f], b, acc);
            }
            int c = t * 16 + rlane;
            float bias = b1[c];
#pragma unroll
            for (int r = 0; r < 4; ++r) {
                int row = q * 4 + r;
                float val = acc[r] * inv * sattr[row] + bias;
                if (c < 384) {                       // uniform per tile (384 = 24*16)
                    float s = val / (1.f + __expf(-val));      // silu
                    smid[row * MID0_S + c] = (bf16_t)s;
                } else {
                    float g = 1.f / (1.f + __expf(-val));      // sigmoid
                    sgate[row * GATE_S + (c - 384)] = (bf16_t)g;
                }
            }
        }
    }
    __syncthreads();

    // ---- Phase 2, l=0: out0 = mid0 @ W2_0 + b2 ----
    {
        const float inv = 0.051031036307982884f;  // 1/sqrt(384)
        bf16x8 am[12];
        int rb = rlane * MID0_S + q * 8;
#pragma unroll
        for (int f = 0; f < 12; ++f) am[f] = *(const bf16x8*)&smid[rb + f * 32];
        for (int t = w; t < 8; t += 4) {
            f32x4 acc = {0.f, 0.f, 0.f, 0.f};
            const bf16_t* wb = wf + OFF_W20 + ((t * 12) << 9) + (lane << 3);
#pragma unroll
            for (int f = 0; f < 12; ++f) {
                bf16x8 b = *(const bf16x8*)(wb + (f << 9));
                acc = mfma16(am[f], b, acc);
            }
            int c = t * 16 + rlane;
            float bias = b2[c];
#pragma unroll
            for (int r = 0; r < 4; ++r) {
                int row = q * 4 + r;
                out[(size_t)(rowbase + row) * 480 + c] = acc[r] * inv * sattr[row] + bias;
            }
        }
    }
    __syncthreads();

    // ---- Phase 1, l=1: h1 = x1@W1_1 * inv * attr * g1 -> mid1 (per i) ----
    {
        const float inv = 0.125f;                 // 1/sqrt(64)
        for (int id = w; id < 36; id += 4) {
            int i = id / 12, t = id - (id / 12) * 12;
            f32x4 acc = {0.f, 0.f, 0.f, 0.f};
            const bf16_t* wb = wf + OFF_W11 + ((t * 2) << 9) + (lane << 3);
#pragma unroll
            for (int f = 0; f < 2; ++f) {
                bf16x8 b = *(const bf16x8*)(wb + (f << 9));
                acc = mfma16(a1[i][f], b, acc);
            }
            int m = t * 16 + rlane;
#pragma unroll
            for (int r = 0; r < 4; ++r) {
                int row = q * 4 + r;
                float g = (float)sgate[row * GATE_S + m];
                smid[i * 3200 + row * MID1_S + m] = (bf16_t)(acc[r] * inv * sattr[row] * g);
            }
        }
    }
    __syncthreads();

    // ---- Phase 2, l=1: out1_i = mid1_i @ W2_1 ----
    {
        const float inv = 0.072168783648703220f;  // 1/sqrt(192)
        for (int id = w; id < 12; id += 4) {
            int i = id >> 2, t = id & 3;
            bf16x8 am[6];
            int rb = i * 3200 + rlane * MID1_S + q * 8;
#pragma unroll
            for (int f = 0; f < 6; ++f) am[f] = *(const bf16x8*)&smid[rb + f * 32];
            f32x4 acc = {0.f, 0.f, 0.f, 0.f};
            const bf16_t* wb = wf + OFF_W21 + ((t * 6) << 9) + (lane << 3);
#pragma unroll
            for (int f = 0; f < 6; ++f) {
                bf16x8 b = *(const bf16x8*)(wb + (f << 9));
                acc = mfma16(am[f], b, acc);
            }
            int o = t * 16 + rlane;
#pragma unroll
            for (int r = 0; r < 4; ++r) {
                int row = q * 4 + r;
                out[(size_t)(rowbase + row) * 480 + 128 + o * 3 + i] = acc[r] * inv * sattr[row];
            }
        }
    }
    __syncthreads();

    // ---- Phase 1, l=2: h2 = x2@W1_2 * inv * attr * g2 -> mid2 (per i) ----
    {
        const float inv = 0.17677669529663689f;   // 1/sqrt(32)
        for (int id = w; id < 30; id += 4) {
            int i = id / 6, t = id - (id / 6) * 6;
            const bf16_t* wb = wf + OFF_W12 + (t << 9) + (lane << 3);
            bf16x8 b = *(const bf16x8*)wb;
            f32x4 acc = {0.f, 0.f, 0.f, 0.f};
            acc = mfma16(a2[i], b, acc);
            int m = t * 16 + rlane;
#pragma unroll
            for (int r = 0; r < 4; ++r) {
                int row = q * 4 + r;
                float g = (float)sgate[row * GATE_S + 192 + m];
                smid[i * 1664 + row * MID2_S + m] = (bf16_t)(acc[r] * inv * sattr[row] * g);
            }
        }
    }
    __syncthreads();

    // ---- Phase 2, l=2: out2_i = mid2_i @ W2_2 ----
    {
        const float inv = 0.10206207261596575f;   // 1/sqrt(96)
        for (int id = w; id < 10; id += 4) {
            int i = id >> 1, t = id & 1;
            bf16x8 am[3];
            int rb = i * 1664 + rlane * MID2_S + q * 8;
#pragma unroll
            for (int f = 0; f < 3; ++f) am[f] = *(const bf16x8*)&smid[rb + f * 32];
            f32x4 acc = {0.f, 0.f, 0.f, 0.f};
            const bf16_t* wb = wf + OFF_W22 + ((t * 3) << 9) + (lane << 3);
#pragma unroll
            for (int f = 0; f < 3; ++f) {
                bf16x8 b = *(const bf16x8*)(wb + (f << 9));
                acc = mfma16(am[f], b, acc);
            }
            int o = t * 16 + rlane;
#pragma unroll
            for (int r = 0; r < 4; ++r) {
                int row = q * 4 + r;
                out[(size_t)(rowbase + row) * 480 + 320 + o * 5 + i] = acc[r] * inv * sattr[row];
            }
        }
    }
}

extern "C" void kernel_launch(void* const* d_in, const int* in_sizes, int n_in,
                              void* d_out, int out_size, void* d_ws, size_t ws_size,
                              hipStream_t stream) {
    const float* x    = (const float*)d_in[0];
    const float* attr = (const float*)d_in[1];
    const float* W10  = (const float*)d_in[2];
    const float* W11  = (const float*)d_in[3];
    const float* W12  = (const float*)d_in[4];
    const float* b1   = (const float*)d_in[5];
    const float* W20  = (const float*)d_in[6];
    const float* W21  = (const float*)d_in[7];
    const float* W22  = (const float*)d_in[8];
    const float* b2   = (const float*)d_in[9];
    float*  out = (float*)d_out;
    bf16_t* wf  = (bf16_t*)d_ws;     // 331,776 B of fragment-ordered bf16 weights

    int N = in_sizes[0] / 480;       // 100000

    prep_weights<<<dim3((W_TOTAL + 255) / 256), dim3(256), 0, stream>>>(
        W10, W11, W12, W20, W21, W22, wf);
    ffn_kernel<<<dim3(N / 16), dim3(256), 0, stream>>>(
        x, attr, b1, b2, wf, out);
}

// Round 2
// 449.019 us; speedup vs baseline: 2.4340x; 2.4340x over previous
//
#include <hip/hip_runtime.h>
#include <hip/hip_bf16.h>

typedef __bf16 bf16_t;
typedef __bf16 bf16x8 __attribute__((ext_vector_type(8)));
typedef float  f32x4  __attribute__((ext_vector_type(4)));

static __device__ __forceinline__ f32x4 mfma16(bf16x8 a, bf16x8 b, f32x4 c) {
    return __builtin_amdgcn_mfma_f32_16x16x32_bf16(a, b, c, 0, 0, 0);
}
static __device__ __forceinline__ float fast_rcp(float x) {
    return __builtin_amdgcn_rcpf(x);
}

// ws fragment-layout weight offsets (bf16 elements). Fragment block = 512
// elems = (64 lanes x 8 elems); block index = tile*frags + f.
#define OFF_W10 0
#define OFF_W11 86016
#define OFF_W12 98304
#define OFF_W20 101376
#define OFF_W21 150528
#define OFF_W22 162816
#define W_TOTAL 165888

__global__ void prep_weights(const float* __restrict__ W10, const float* __restrict__ W11,
                             const float* __restrict__ W12, const float* __restrict__ W20,
                             const float* __restrict__ W21, const float* __restrict__ W22,
                             bf16_t* __restrict__ ws) {
    int idx = blockIdx.x * 256 + threadIdx.x;
    if (idx >= W_TOTAL) return;
    const float* src; int K, N, off;
    if      (idx < OFF_W11) { src = W10; K = 128; N = 672; off = OFF_W10; }
    else if (idx < OFF_W12) { src = W11; K = 64;  N = 192; off = OFF_W11; }
    else if (idx < OFF_W20) { src = W12; K = 32;  N = 96;  off = OFF_W12; }
    else if (idx < OFF_W21) { src = W20; K = 384; N = 128; off = OFF_W20; }
    else if (idx < OFF_W22) { src = W21; K = 192; N = 64;  off = OFF_W21; }
    else                    { src = W22; K = 96;  N = 32;  off = OFF_W22; }
    int local = idx - off;
    int j    = local & 7;
    int lane = (local >> 3) & 63;
    int tf   = local >> 9;
    int frags = K >> 5;
    int f    = tf % frags;
    int tile = tf / frags;
    int k = f * 32 + ((lane >> 4) << 3) + j;
    int n = tile * 16 + (lane & 15);
    ws[idx] = (bf16_t)src[k * N + n];
}

// LDS plan (bf16 elems in smid, total 17920 = 35840 B):
//   [0,9600)     : xde (7808 used) during S0/S1, then mid1 (3 planes x 3200) in S2
//   [9600,17920) : mid0 (6272 used) in S1/S2, then mid2 (5 planes x 1664) in S3
// sgate separate (gates live S1..S3). Barriers: B1 stage, B2 after P1l0,
// B3 after {P2l0,P1l1}, B4 after {P1l2,P2l1}.
#define XDE_S   488
#define MID0_S  392
#define MID1_S  200
#define MID2_S  104
#define GATE_S  296
#define MID0_B  9600
#define MID2_B  9600

__global__ __launch_bounds__(256, 3)
void ffn_kernel(const float* __restrict__ x, const float* __restrict__ attr,
                const float* __restrict__ b1, const float* __restrict__ b2,
                const bf16_t* __restrict__ wf, float* __restrict__ out) {
    __shared__ bf16_t smid[17920];
    __shared__ bf16_t sgate[16 * GATE_S];
    __shared__ float  sattr[16];
    __shared__ float  sb1[672];
    __shared__ float  sb2[128];

    const int tid   = threadIdx.x;
    const int lane  = tid & 63;
    const int w     = tid >> 6;
    const int rlane = lane & 15;
    const int q     = lane >> 4;
    const int rowbase = blockIdx.x * 16;

    // ---------------- S0: stage x (de-interleaved bf16), biases, attr ----
    for (int it = 0; it < 8; ++it) {
        int idx = tid + it * 256;
        if (idx < 1920) {
            int row = idx / 120;
            int c4  = idx - row * 120;
            const float4 v = ((const float4*)(x + (size_t)(rowbase + row) * 480))[c4];
            float vals[4] = {v.x, v.y, v.z, v.w};
            int base = c4 * 4;
#pragma unroll
            for (int e = 0; e < 4; ++e) {
                int col = base + e;
                int dc;
                if (col < 128) dc = col;
                else if (col < 320) { int r = col - 128; int m = r / 3; int i = r - m * 3; dc = 128 + i * 64 + m; }
                else                { int r = col - 320; int m = r / 5; int i = r - m * 5; dc = 320 + i * 32 + m; }
                smid[row * XDE_S + dc] = (bf16_t)vals[e];
            }
        }
    }
    for (int i = tid; i < 672; i += 256) sb1[i] = b1[i];
    if (tid < 128) sb2[tid] = b2[tid];
    if (tid < 16)  sattr[tid] = attr[rowbase + tid];
    __syncthreads();                                   // B1

    // per-wave attr registers (row = q*4 + r)
    float sat[4];
#pragma unroll
    for (int r = 0; r < 4; ++r) sat[r] = sattr[q * 4 + r];

    // ---------------- S1: extract A frags; P1l0 (pipelined) --------------
    bf16x8 a0[4], a1[3][2], a2[5];
    {
        int rb = rlane * XDE_S + q * 8;
#pragma unroll
        for (int f = 0; f < 4; ++f) a0[f] = *(const bf16x8*)&smid[rb + f * 32];
#pragma unroll
        for (int i = 0; i < 3; ++i)
#pragma unroll
            for (int f = 0; f < 2; ++f) a1[i][f] = *(const bf16x8*)&smid[rb + 128 + i * 64 + f * 32];
#pragma unroll
        for (int i = 0; i < 5; ++i) a2[i] = *(const bf16x8*)&smid[rb + 320 + i * 32];
    }

    {
        const float inv = 0.088388347648318447f;       // 1/sqrt(128)
        const bf16_t* base10 = wf + OFF_W10 + (lane << 3);
        int t = w;
        bf16x8 bc[4];
        {
            const bf16_t* p = base10 + ((t * 4) << 9);
#pragma unroll
            for (int f = 0; f < 4; ++f) bc[f] = *(const bf16x8*)(p + (f << 9));
        }
        while (t < 42) {
            int tn = t + 4;
            bf16x8 bn[4] = {bc[0], bc[1], bc[2], bc[3]};
            if (tn < 42) {
                const bf16_t* p = base10 + ((tn * 4) << 9);
#pragma unroll
                for (int f = 0; f < 4; ++f) bn[f] = *(const bf16x8*)(p + (f << 9));
            }
            f32x4 acc = {0.f, 0.f, 0.f, 0.f};
#pragma unroll
            for (int f = 0; f < 4; ++f) acc = mfma16(a0[f], bc[f], acc);

            int c = t * 16 + rlane;
            float bias = sb1[c];
            if (t < 24) {                              // scalars -> silu -> mid0
#pragma unroll
                for (int r = 0; r < 4; ++r) {
                    float v = acc[r] * inv * sat[r] + bias;
                    float s = v * fast_rcp(1.f + __expf(-v));
                    smid[MID0_B + (q * 4 + r) * MID0_S + c] = (bf16_t)s;
                }
            } else {                                   // gates -> sigmoid
#pragma unroll
                for (int r = 0; r < 4; ++r) {
                    float v = acc[r] * inv * sat[r] + bias;
                    float g = fast_rcp(1.f + __expf(-v));
                    sgate[(q * 4 + r) * GATE_S + (c - 384)] = (bf16_t)g;
                }
            }
#pragma unroll
            for (int f = 0; f < 4; ++f) bc[f] = bn[f];
            t = tn;
        }
    }
    __syncthreads();                                   // B2

    // ---------------- S2: P2l0 (out cols 0..127) + P1l1 (mid1) -----------
    {
        const float inv = 0.051031036307982884f;       // 1/sqrt(384)
        bf16x8 am[12];
        int rb = MID0_B + rlane * MID0_S + q * 8;
#pragma unroll
        for (int f = 0; f < 12; ++f) am[f] = *(const bf16x8*)&smid[rb + f * 32];
#pragma unroll 2
        for (int t = w; t < 8; t += 4) {
            const bf16_t* p = wf + OFF_W20 + ((t * 12) << 9) + (lane << 3);
            f32x4 acc = {0.f, 0.f, 0.f, 0.f};
#pragma unroll
            for (int f = 0; f < 12; ++f) {
                bf16x8 b = *(const bf16x8*)(p + (f << 9));
                acc = mfma16(am[f], b, acc);
            }
            int c = t * 16 + rlane;
            float bias = sb2[c];
#pragma unroll
            for (int r = 0; r < 4; ++r)
                out[(size_t)(rowbase + q * 4 + r) * 480 + c] = acc[r] * inv * sat[r] + bias;
        }
    }
    {
        const float inv = 0.125f;                      // 1/sqrt(64)
#pragma unroll 3
        for (int t = w; t < 12; t += 4) {
            const bf16_t* p = wf + OFF_W11 + ((t * 2) << 9) + (lane << 3);
            bf16x8 b0 = *(const bf16x8*)p;
            bf16x8 b1f = *(const bf16x8*)(p + 512);
            f32x4 acc[3];
#pragma unroll
            for (int i = 0; i < 3; ++i) {
                f32x4 a = {0.f, 0.f, 0.f, 0.f};
                a = mfma16(a1[i][0], b0, a);
                a = mfma16(a1[i][1], b1f, a);
                acc[i] = a;
            }
            int m = t * 16 + rlane;
#pragma unroll
            for (int r = 0; r < 4; ++r) {
                int row = q * 4 + r;
                float g = (float)sgate[row * GATE_S + m] * inv * sat[r];
#pragma unroll
                for (int i = 0; i < 3; ++i)
                    smid[i * 3200 + row * MID1_S + m] = (bf16_t)(acc[i][r] * g);
            }
        }
    }
    __syncthreads();                                   // B3

    // ---------------- S3: P1l2 (mid2) + P2l1 (out cols 128..319) ---------
    {
        const float inv = 0.17677669529663689f;        // 1/sqrt(32)
#pragma unroll 2
        for (int t = w; t < 6; t += 4) {
            const bf16_t* p = wf + OFF_W12 + (t << 9) + (lane << 3);
            bf16x8 b = *(const bf16x8*)p;
            f32x4 acc[5];
#pragma unroll
            for (int i = 0; i < 5; ++i) {
                f32x4 a = {0.f, 0.f, 0.f, 0.f};
                acc[i] = mfma16(a2[i], b, a);
            }
            int m = t * 16 + rlane;
#pragma unroll
            for (int r = 0; r < 4; ++r) {
                int row = q * 4 + r;
                float g = (float)sgate[row * GATE_S + 192 + m] * inv * sat[r];
#pragma unroll
                for (int i = 0; i < 5; ++i)
                    smid[MID2_B + i * 1664 + row * MID2_S + m] = (bf16_t)(acc[i][r] * g);
            }
        }
    }
    {
        const float inv = 0.072168783648703220f;       // 1/sqrt(192)
        int t = w;                                     // 4 tiles exactly
        const bf16_t* p = wf + OFF_W21 + ((t * 6) << 9) + (lane << 3);
        bf16x8 b[6];
#pragma unroll
        for (int f = 0; f < 6; ++f) b[f] = *(const bf16x8*)(p + (f << 9));
        f32x4 acc[3];
#pragma unroll
        for (int i = 0; i < 3; ++i) {
            bf16x8 am[6];
            int rb = i * 3200 + rlane * MID1_S + q * 8;
#pragma unroll
            for (int f = 0; f < 6; ++f) am[f] = *(const bf16x8*)&smid[rb + f * 32];
            f32x4 a = {0.f, 0.f, 0.f, 0.f};
#pragma unroll
            for (int f = 0; f < 6; ++f) a = mfma16(am[f], b[f], a);
            acc[i] = a;
        }
        int o = t * 16 + rlane;
#pragma unroll
        for (int r = 0; r < 4; ++r) {
            float s = inv * sat[r];
            float* dst = out + (size_t)(rowbase + q * 4 + r) * 480 + 128 + o * 3;
            dst[0] = acc[0][r] * s;
            dst[1] = acc[1][r] * s;
            dst[2] = acc[2][r] * s;
        }
    }
    __syncthreads();                                   // B4

    // ---------------- S4: P2l2 (out cols 320..479) -----------------------
    if (w < 2) {
        const float inv = 0.10206207261596575f;        // 1/sqrt(96)
        int t = w;                                     // 2 tiles
        const bf16_t* p = wf + OFF_W22 + ((t * 3) << 9) + (lane << 3);
        bf16x8 b[3];
#pragma unroll
        for (int f = 0; f < 3; ++f) b[f] = *(const bf16x8*)(p + (f << 9));
        f32x4 acc[5];
#pragma unroll
        for (int i = 0; i < 5; ++i) {
            bf16x8 am[3];
            int rb = MID2_B + i * 1664 + rlane * MID2_S + q * 8;
#pragma unroll
            for (int f = 0; f < 3; ++f) am[f] = *(const bf16x8*)&smid[rb + f * 32];
            f32x4 a = {0.f, 0.f, 0.f, 0.f};
#pragma unroll
            for (int f = 0; f < 3; ++f) a = mfma16(am[f], b[f], a);
            acc[i] = a;
        }
        int o = t * 16 + rlane;
#pragma unroll
        for (int r = 0; r < 4; ++r) {
            float s = inv * sat[r];
            float* dst = out + (size_t)(rowbase + q * 4 + r) * 480 + 320 + o * 5;
#pragma unroll
            for (int i = 0; i < 5; ++i) dst[i] = acc[i][r] * s;
        }
    }
}

extern "C" void kernel_launch(void* const* d_in, const int* in_sizes, int n_in,
                              void* d_out, int out_size, void* d_ws, size_t ws_size,
                              hipStream_t stream) {
    const float* x    = (const float*)d_in[0];
    const float* attr = (const float*)d_in[1];
    const float* W10  = (const float*)d_in[2];
    const float* W11  = (const float*)d_in[3];
    const float* W12  = (const float*)d_in[4];
    const float* b1   = (const float*)d_in[5];
    const float* W20  = (const float*)d_in[6];
    const float* W21  = (const float*)d_in[7];
    const float* W22  = (const float*)d_in[8];
    const float* b2   = (const float*)d_in[9];
    float*  out = (float*)d_out;
    bf16_t* wf  = (bf16_t*)d_ws;

    int N = in_sizes[0] / 480;       // 100000

    prep_weights<<<dim3((W_TOTAL + 255) / 256), dim3(256), 0, stream>>>(
        W10, W11, W12, W20, W21, W22, wf);
    ffn_kernel<<<dim3(N / 16), dim3(256), 0, stream>>>(
        x, attr, b1, b2, wf, out);
}